// Round 1
// 282.317 us; speedup vs baseline: 1.0135x; 1.0135x over previous
//
#include <hip/hip_runtime.h>
#include <hip/hip_fp16.h>
#include <math.h>

#define C_S 256
#define NUM_HEADS 8
#define HEAD_DIM 32
#define TOTAL 256
#define S_DIM 256
#define I_DIM 256
#define NROWS (S_DIM * I_DIM)   // 65536
#define LN_EPS 1e-5f
#define QSCALE 0.25503534f      // log2(e)/sqrt(32)

typedef _Float16 f16x8 __attribute__((ext_vector_type(8)));   // 8 fp16 = 4 VGPR
typedef __attribute__((ext_vector_type(4))) float f32x4;

__device__ __forceinline__ ushort f2h(float x) {
  return __half_as_ushort(__float2half(x));      // RNE
}
__device__ __forceinline__ float h2f(ushort u) {
  return __half2float(__ushort_as_half(u));
}
// async global->LDS, 16B per lane; lds base must be wave-uniform.
__device__ __forceinline__ void gl16(const void* g, void* l) {
  __builtin_amdgcn_global_load_lds(
      (const __attribute__((address_space(1))) unsigned*)g,
      (__attribute__((address_space(3))) unsigned*)l, 16, 0, 0);
}

// ---------------------------------------------------------------------------
// prep_w: transpose + fp16-convert weights once.
// QKVG -> combined [1024][256] fp16 (row = mat*256+n, k contiguous);
// Wo -> [256][256] fp16.
// ---------------------------------------------------------------------------
__global__ __launch_bounds__(256) void prep_w_kernel(
    const float* __restrict__ Wq, const float* __restrict__ Wk,
    const float* __restrict__ Wv, const float* __restrict__ Wg,
    const float* __restrict__ Wo,
    ushort* __restrict__ Wch, ushort* __restrict__ Woh) {
  const int b = blockIdx.x;            // 0..1279
  const int mat = b >> 8, n = b & 255;
  const int k = threadIdx.x;
  const float* W = (mat == 0) ? Wq : (mat == 1) ? Wk
                  : (mat == 2) ? Wv : (mat == 3) ? Wg : Wo;
  ushort h = f2h(W[(size_t)k * 256 + n]);
  if (mat < 4) Wch[((size_t)(mat * 256 + n)) * 256 + k] = h;
  else         Woh[(size_t)n * 256 + k] = h;
}

// ---------------------------------------------------------------------------
// prep_x: LN stats + apply + fp16-convert, once. One wave per row.
// X fp16 lives in d_out (dead until out_kernel overwrites it).
// ---------------------------------------------------------------------------
__global__ __launch_bounds__(256) void prep_x_kernel(
    const float* __restrict__ msa, const float* __restrict__ gamma,
    const float* __restrict__ beta, ushort* __restrict__ Xh) {
  const int row  = blockIdx.x * 4 + (threadIdx.x >> 6);
  const int lane = threadIdx.x & 63;
  float4 v = ((const float4*)(msa + (size_t)row * C_S))[lane];
  float sum = v.x + v.y + v.z + v.w;
  float sq  = v.x*v.x + v.y*v.y + v.z*v.z + v.w*v.w;
  #pragma unroll
  for (int off = 1; off < 64; off <<= 1) {
    sum += __shfl_xor(sum, off);
    sq  += __shfl_xor(sq, off);
  }
  float mu = sum * (1.0f / 256.0f);
  float rs = rsqrtf(sq * (1.0f / 256.0f) - mu * mu + LN_EPS);
  float4 gv = ((const float4*)gamma)[lane];
  float4 bv = ((const float4*)beta)[lane];
  ushort4 hh;
  hh.x = f2h((v.x - mu) * rs * gv.x + bv.x);
  hh.y = f2h((v.y - mu) * rs * gv.y + bv.y);
  hh.z = f2h((v.z - mu) * rs * gv.z + bv.z);
  hh.w = f2h((v.w - mu) * rs * gv.w + bv.w);
  *(ushort4*)(Xh + (size_t)row * 256 + lane * 4) = hh;
}

// ---------------------------------------------------------------------------
// fused_attn: one block per (i,h). Each wave owns 64 s/t rows.
//  LDS cut to 53.8 KB (3 blocks/CU):
//   Kls[256][40]  K[t][d]                                       20.0 KB
//   Vth[32][264]  V^T[d][t]  (filled by swapped-operand MFMA)   16.5 KB
//   Pls[256][32]  P / Q staging, column-XOR-swizzled            16.0 KB
//  Phase A: K^T GEMM (normal) + V^T GEMM with SWAPPED operands
//           (mfma(xb, wv) -> D col=d,row=t) so V^T stores are packed b64.
//  Phase B: Q^T (scaled, staged via swizzled Pls -> B-operand regs),
//           G^T (stays in f32 regs; D-layout col=s,row=d matches oacc).
//  One __syncthreads. Chunk loop runs at HALF-chunk granularity (32 t):
//  QK(mt 0,1) -> P(32 cols) -> PV(ks=0) -> QK(mt 2,3) -> P -> PV(ks=1),
//  so P needs only 32 columns. lpart sums the f32 exp2 values (no h2f).
// ---------------------------------------------------------------------------
__global__ __launch_bounds__(256, 3) void fused_attn_kernel(
    const ushort* __restrict__ Xh,    // [65536][256], row = s*256+i
    const ushort* __restrict__ Wch,   // [1024][256], row = mat*256+n
    const float* __restrict__ bg,
    ushort* __restrict__ Oh) {        // (i,h,s,d) fp16
  __shared__ __align__(16) ushort Kls[256][40];   // 20.0 KB  K[t][d]
  __shared__ __align__(16) ushort Vth[32][264];   // 16.5 KB  V^T[d][t]
  __shared__ __align__(16) ushort Pls[256][32];   // 16.0 KB  P (+Q staging)

  const int bid = blockIdx.x;
  const int xcd = bid & 7, j = bid >> 3;
  const int h = j & 7;
  const int i = (xcd << 5) + (j >> 3);            // 32 consecutive i per XCD
  const int ih = i * NUM_HEADS + h;
  const int tid = threadIdx.x;
  const int wave = tid >> 6, lane = tid & 63;
  const int lr = lane & 15, quad = lane >> 4;
  const int s_base = wave * 64;
  const size_t hbase = (size_t)ih * (S_DIM * HEAD_DIM);

  // Pls column swizzle: stored col = true_col ^ ((s&3)*8); s&3 == lr&3.
  // write col (4-aligned): ((m ^ lrb1)<<4) + (qw<<2); read base: prd.
  const int lrb0 = lr & 1, lrb1 = (lr >> 1) & 1;
  const int qw  = quad ^ (lrb0 << 1);
  const int prd = (quad ^ (lr & 3)) << 3;

  // X B-frag base: row (s,i) = (s*256+i), element quad*8 within k-chunk
  const ushort* xr0 = Xh + ((size_t)(s_base + lr) * 256 + i) * 256 + quad * 8;
  // W^T A-frag base: row = mat*256 + h*32 + (mt*16+lr)
  const ushort* wr0 = Wch + ((size_t)(h * 32 + lr)) * 256 + quad * 8;

  // ---- Phase A: K^T (mat 1), V^T (mat 2, swapped operands) ----
  f32x4 kacc[2][4] = {}, vacc[2][4] = {};
  #pragma unroll
  for (int kb = 0; kb < 8; ++kb) {
    f16x8 xb[4];
    #pragma unroll
    for (int nt = 0; nt < 4; ++nt)
      xb[nt] = *(const f16x8*)(xr0 + (size_t)nt * 16 * 65536 + kb * 32);
    f16x8 wk[2], wv[2];
    #pragma unroll
    for (int mt = 0; mt < 2; ++mt) {
      wk[mt] = *(const f16x8*)(wr0 + (size_t)1 * 65536 + mt * 4096 + kb * 32);
      wv[mt] = *(const f16x8*)(wr0 + (size_t)2 * 65536 + mt * 4096 + kb * 32);
    }
    #pragma unroll
    for (int mt = 0; mt < 2; ++mt)
      #pragma unroll
      for (int nt = 0; nt < 4; ++nt) {
        kacc[mt][nt] = __builtin_amdgcn_mfma_f32_16x16x32_f16(wk[mt], xb[nt], kacc[mt][nt], 0, 0, 0);
        // swapped: D col = d (lr), row = t (quad*4+reg) -> packed V^T store
        vacc[mt][nt] = __builtin_amdgcn_mfma_f32_16x16x32_f16(xb[nt], wv[mt], vacc[mt][nt], 0, 0, 0);
      }
  }
  #pragma unroll
  for (int mt = 0; mt < 2; ++mt)
    #pragma unroll
    for (int nt = 0; nt < 4; ++nt) {
      // K: D col = t (nt*16+lr), row = d (mt*16+quad*4+reg)
      const int t = s_base + nt * 16 + lr;
      ushort4 kp;
      kp.x = f2h(kacc[mt][nt][0]); kp.y = f2h(kacc[mt][nt][1]);
      kp.z = f2h(kacc[mt][nt][2]); kp.w = f2h(kacc[mt][nt][3]);
      *(ushort4*)&Kls[t][mt * 16 + quad * 4] = kp;
      // V (swapped): lane holds V^T[d = mt*16+lr][t = s_base+nt*16+quad*4+reg]
      ushort4 vp;
      vp.x = f2h(vacc[mt][nt][0]); vp.y = f2h(vacc[mt][nt][1]);
      vp.z = f2h(vacc[mt][nt][2]); vp.w = f2h(vacc[mt][nt][3]);
      *(ushort4*)&Vth[mt * 16 + lr][s_base + nt * 16 + quad * 4] = vp;
    }

  // ---- Phase B: Q^T (mat 0), G^T (mat 3) ----
  f32x4 qacc[2][4] = {}, gacc[2][4] = {};
  #pragma unroll
  for (int kb = 0; kb < 8; ++kb) {
    f16x8 xb[4];
    #pragma unroll
    for (int nt = 0; nt < 4; ++nt)
      xb[nt] = *(const f16x8*)(xr0 + (size_t)nt * 16 * 65536 + kb * 32);
    f16x8 wq[2], wg[2];
    #pragma unroll
    for (int mt = 0; mt < 2; ++mt) {
      wq[mt] = *(const f16x8*)(wr0 + (size_t)0 * 65536 + mt * 4096 + kb * 32);
      wg[mt] = *(const f16x8*)(wr0 + (size_t)3 * 65536 + mt * 4096 + kb * 32);
    }
    #pragma unroll
    for (int mt = 0; mt < 2; ++mt)
      #pragma unroll
      for (int nt = 0; nt < 4; ++nt) {
        qacc[mt][nt] = __builtin_amdgcn_mfma_f32_16x16x32_f16(wq[mt], xb[nt], qacc[mt][nt], 0, 0, 0);
        gacc[mt][nt] = __builtin_amdgcn_mfma_f32_16x16x32_f16(wg[mt], xb[nt], gacc[mt][nt], 0, 0, 0);
      }
  }
  // Q -> wave-private swizzled Pls rows, then frag regs (all pre-barrier)
  #pragma unroll
  for (int mt = 0; mt < 2; ++mt) {
    const int cw = ((mt ^ lrb1) << 4) + (qw << 2);
    #pragma unroll
    for (int nt = 0; nt < 4; ++nt) {
      const int s = s_base + nt * 16 + lr;
      ushort4 qp;
      qp.x = f2h(qacc[mt][nt][0] * QSCALE); qp.y = f2h(qacc[mt][nt][1] * QSCALE);
      qp.z = f2h(qacc[mt][nt][2] * QSCALE); qp.w = f2h(qacc[mt][nt][3] * QSCALE);
      *(ushort4*)&Pls[s][cw] = qp;
    }
  }
  f16x8 qf[4];
  #pragma unroll
  for (int ns = 0; ns < 4; ++ns)
    qf[ns] = *(const f16x8*)&Pls[s_base + ns * 16 + lr][prd];
  // G: sigmoid in registers; layout (col=s, row=d) == oacc layout
  f32x4 gv[2][4];
  #pragma unroll
  for (int mt = 0; mt < 2; ++mt) {
    float4 bgv = *(const float4*)(bg + h * 32 + mt * 16 + quad * 4);
    float bga[4] = {bgv.x, bgv.y, bgv.z, bgv.w};
    #pragma unroll
    for (int nt = 0; nt < 4; ++nt)
      #pragma unroll
      for (int reg = 0; reg < 4; ++reg)
        gv[mt][nt][reg] = 1.0f / (1.0f + __expf(-(gacc[mt][nt][reg] + bga[reg])));
  }

  __syncthreads();   // K/V visible; lgkmcnt(0) also fences the Q staging reads

  // ---- attention chunk loop, half-chunk (32-t) granularity ----
  f32x4 oacc[2][4] = {};
  float lpart[4] = {};
  #pragma unroll 1
  for (int c = 0; c < 4; ++c) {
    const int t0 = c * 64;
    f16x8 kf[4];
    #pragma unroll
    for (int mt = 0; mt < 4; ++mt)
      kf[mt] = *(const f16x8*)&Kls[t0 + mt * 16 + lr][quad * 8];
    #pragma unroll
    for (int half = 0; half < 2; ++half) {
      #pragma unroll
      for (int m2 = 0; m2 < 2; ++m2) {
        const int mt = half * 2 + m2;
        const int cw = ((m2 ^ lrb1) << 4) + (qw << 2);
        #pragma unroll
        for (int ns = 0; ns < 4; ++ns) {
          f32x4 sc = {};
          sc = __builtin_amdgcn_mfma_f32_16x16x32_f16(kf[mt], qf[ns], sc, 0, 0, 0);
          float e0 = exp2f(sc[0]), e1 = exp2f(sc[1]);
          float e2 = exp2f(sc[2]), e3 = exp2f(sc[3]);
          lpart[ns] += (e0 + e1) + (e2 + e3);          // f32 sum, no h2f
          ushort4 pk;
          pk.x = f2h(e0); pk.y = f2h(e1); pk.z = f2h(e2); pk.w = f2h(e3);
          *(ushort4*)&Pls[s_base + ns * 16 + lr][cw] = pk;
        }
      }
      const int tq = t0 + half * 32 + quad * 8;
      f16x8 v0 = *(const f16x8*)&Vth[lr][tq];
      f16x8 v1 = *(const f16x8*)&Vth[16 + lr][tq];
      #pragma unroll
      for (int ns = 0; ns < 4; ++ns) {
        f16x8 pf = *(const f16x8*)&Pls[s_base + ns * 16 + lr][prd];
        oacc[0][ns] = __builtin_amdgcn_mfma_f32_16x16x32_f16(v0, pf, oacc[0][ns], 0, 0, 0);
        oacc[1][ns] = __builtin_amdgcn_mfma_f32_16x16x32_f16(v1, pf, oacc[1][ns], 0, 0, 0);
      }
    }
  }

  float invl[4];
  #pragma unroll
  for (int ns = 0; ns < 4; ++ns) {
    float v = lpart[ns];
    v += __shfl_xor(v, 16);
    v += __shfl_xor(v, 32);
    invl[ns] = 1.0f / v;
  }

  // ---- epilogue: gate from registers, write O fp16 (i,h,s,d) ----
  #pragma unroll
  for (int ns = 0; ns < 4; ++ns) {
    const int s = s_base + ns * 16 + lr;
    #pragma unroll
    for (int md = 0; md < 2; ++md) {
      const int d0 = md * 16 + quad * 4;
      ushort4 ov;
      ov.x = f2h(gv[md][ns][0] * oacc[md][ns][0] * invl[ns]);
      ov.y = f2h(gv[md][ns][1] * oacc[md][ns][1] * invl[ns]);
      ov.z = f2h(gv[md][ns][2] * oacc[md][ns][2] * invl[ns]);
      ov.w = f2h(gv[md][ns][3] * oacc[md][ns][3] * invl[ns]);
      *(ushort4*)(Oh + hbase + (size_t)s * HEAD_DIM + d0) = ov;
    }
  }
}

// ---------------------------------------------------------------------------
// out: pure fp16 GEMM (unchanged). A = O fp16 (i,h,s,d);
// B = Wo^T fp16 [n][k]. m-tile = (s fixed, 128 i's); BK=64 = two heads/iter.
// ---------------------------------------------------------------------------
__global__ __launch_bounds__(256) void out_kernel(
    const ushort* __restrict__ Oh, const ushort* __restrict__ Woh,
    const float* __restrict__ bo, float* __restrict__ out) {
  __shared__ __align__(16) ushort At0[128 * 32];
  __shared__ __align__(16) ushort At1[128 * 32];
  __shared__ __align__(16) ushort Bt0[128 * 32];
  __shared__ __align__(16) ushort Bt1[128 * 32];

  const int bid = blockIdx.x;                    // 0..1023
  const int xcd = bid & 7;
  const int j   = bid >> 3;                      // 0..127
  const int ntile = j & 1;
  const int rg    = (xcd << 6) + (j >> 1);       // 0..511
  const int n0 = ntile * 128;
  const int s  = rg >> 1;
  const int i0 = (rg & 1) * 128;
  const int tid = threadIdx.x;
  const int wave = tid >> 6, lane = tid & 63;
  const int wm = wave >> 1, wn = wave & 1;
  const int lr = lane & 15, quad = lane >> 4;
  const int fsw = (quad ^ ((lr >> 1) & 3)) * 8;

  const int slot = wave * 64 + lane;
  const int row0 = slot >> 2;
  const int kc   = ((slot & 3) ^ ((row0 >> 1) & 3)) * 8;

  const ushort* pA = Oh + (size_t)(i0 + row0) * 65536 + (size_t)s * 32 + kc;
  const ushort* pB = Woh + (size_t)(n0 + row0) * 256 + kc;
  const int ld0 = wave * 512;
  const int ld1 = 2048 + wave * 512;

  f32x4 acc[4][4] = {};

  for (int kk = 0; kk < 4; ++kk) {
    __syncthreads();
    gl16(pA,               At0 + ld0); gl16(pA + (size_t)64 * 65536,        At0 + ld1);
    gl16(pA + 8192,        At1 + ld0); gl16(pA + (size_t)64 * 65536 + 8192, At1 + ld1);
    gl16(pB,               Bt0 + ld0); gl16(pB + 64 * 256,                  Bt0 + ld1);
    gl16(pB + 32,          Bt1 + ld0); gl16(pB + 64 * 256 + 32,             Bt1 + ld1);
    pA += 16384;                                  // next head pair
    pB += 64;
    __syncthreads();

    f16x8 a0[4], a1[4], b0[4], b1[4];
    #pragma unroll
    for (int mt = 0; mt < 4; ++mt) {
      const int off = (wm * 64 + mt * 16 + lr) * 32 + fsw;
      a0[mt] = *(const f16x8*)&At0[off];
      a1[mt] = *(const f16x8*)&At1[off];
    }
    #pragma unroll
    for (int nt = 0; nt < 4; ++nt) {
      const int off = (wn * 64 + nt * 16 + lr) * 32 + fsw;
      b0[nt] = *(const f16x8*)&Bt0[off];
      b1[nt] = *(const f16x8*)&Bt1[off];
    }
    #pragma unroll
    for (int mt = 0; mt < 4; ++mt)
      #pragma unroll
      for (int nt = 0; nt < 4; ++nt) {
        acc[mt][nt] = __builtin_amdgcn_mfma_f32_16x16x32_f16(a0[mt], b0[nt], acc[mt][nt], 0, 0, 0);
        acc[mt][nt] = __builtin_amdgcn_mfma_f32_16x16x32_f16(a1[mt], b1[nt], acc[mt][nt], 0, 0, 0);
      }
  }

  #pragma unroll
  for (int nt = 0; nt < 4; ++nt) {
    const int col = n0 + wn * 64 + nt * 16 + lr;
    const float b = bo[col];
    #pragma unroll
    for (int mt = 0; mt < 4; ++mt)
      #pragma unroll
      for (int reg = 0; reg < 4; ++reg) {
        const int mloc = wm * 64 + mt * 16 + quad * 4 + reg;
        out[((size_t)s * 256 + i0 + mloc) * C_S + col] = acc[mt][nt][reg] + b;
      }
  }
}

// ---------------------------------------------------------------------------
extern "C" void kernel_launch(void* const* d_in, const int* in_sizes, int n_in,
                              void* d_out, int out_size, void* d_ws, size_t ws_size,
                              hipStream_t stream) {
  const float* msa   = (const float*)d_in[0];
  const float* gamma = (const float*)d_in[1];
  const float* beta  = (const float*)d_in[2];
  const float* Wq    = (const float*)d_in[3];
  const float* Wk    = (const float*)d_in[4];
  const float* Wv    = (const float*)d_in[5];
  const float* Wg    = (const float*)d_in[6];
  const float* bg    = (const float*)d_in[7];
  const float* Wo    = (const float*)d_in[8];
  const float* bo    = (const float*)d_in[9];
  float* out = (float*)d_out;

  const size_t PLANE = (size_t)NROWS * TOTAL;    // 16.78M elements
  // ws: O fp16 (33.5 MB) + W fp16 (0.66 MB)
  ushort* Oh  = (ushort*)d_ws;                   // (i,h,s,d)
  ushort* Wch = Oh + PLANE;                      // [1024][256]
  ushort* Woh = Wch + 1024 * 256;                // [256][256]
  // X fp16 lives in d_out (33.5 MB of 67 MB, dead before out_kernel writes)
  ushort* Xh = (ushort*)d_out;

  prep_w_kernel<<<1280, 256, 0, stream>>>(Wq, Wk, Wv, Wg, Wo, Wch, Woh);
  prep_x_kernel<<<NROWS / 4, 256, 0, stream>>>(msa, gamma, beta, Xh);
  fused_attn_kernel<<<I_DIM * NUM_HEADS, 256, 0, stream>>>(Xh, Wch, bg, Oh);
  out_kernel<<<1024, 256, 0, stream>>>(Oh, Woh, bo, out);
}